// Round 18
// baseline (234.940 us; speedup 1.0000x reference)
//
#include <hip/hip_runtime.h>
#include <cstdint>
#include <cstddef>

#define N_NODES 50000
#define N_EDGES 800000
#define HDIM 128
#define TROUNDS 2
#define NTILES 3125
#define PACK_PER_T (416 * 64)   // 128 W1 frag-rows + 288 W2 frag-rows
#define PACK_BLOCKS ((TROUNDS * PACK_PER_T) / 256)  // 208
#define CAST_BLOCKS ((N_NODES * HDIM / 4 + 255) / 256)  // 6250
#define MAXDEG 64
#define NBUK 196                // buckets of 256 node-ids (dst >> 8)
#define BCAP 4608               // per-bucket capacity (mean 4082, +8 sigma)
#define BCE 2048                // edges per bin_count block
#define NBC ((N_EDGES + BCE - 1) / BCE)  // 391

typedef __attribute__((ext_vector_type(8))) _Float16 half8v;
typedef __attribute__((ext_vector_type(2))) _Float16 half2v;
typedef __attribute__((ext_vector_type(4))) float f32x4;
typedef unsigned short ushort_t;
typedef unsigned long long u64;

#define GLD_LDS(gp, lp)                                                        \
  __builtin_amdgcn_global_load_lds(                                            \
      (__attribute__((address_space(1))) const void*)(gp),                     \
      (__attribute__((address_space(3))) void*)(lp), 16, 0, 0)

static __device__ __forceinline__ float sigmoidf_(float x) {
  return 1.0f / (1.0f + __expf(-x));
}
static __device__ __forceinline__ float tanhf_(float x) {
  float xc = fminf(15.0f, fmaxf(-15.0f, x));
  float a = __expf(2.0f * xc);
  return (a - 1.0f) / (a + 1.0f);
}
static __device__ __forceinline__ float f16bits2f(uint32_t hb) {
  ushort_t u = (ushort_t)hb;
  _Float16 h;
  __builtin_memcpy(&h, &u, 2);
  return (float)h;
}

// ---------------- one-shot setup: weight pack + hv fp16 cast + bcur zero ----------------
// W1p[t][jt(16)][kt(8)][lane][8]  fp16, chunk/jt = 8 KB
// W2p[t][chunk(24)=jt*3+p][idx(12)][lane][8] fp16, chunk = 12 KB
__global__ void pack_cast(const float* __restrict__ Wmsg, const float* __restrict__ Wih,
                          const float* __restrict__ Whh, const float* __restrict__ hv,
                          _Float16* __restrict__ W1p, _Float16* __restrict__ W2p,
                          float* __restrict__ we, _Float16* __restrict__ hvh,
                          int* __restrict__ bcur) {
  if (blockIdx.x == 0 && threadIdx.x < NBUK) bcur[threadIdx.x] = 0;
  if (blockIdx.x >= PACK_BLOCKS) {
    int i = (blockIdx.x - PACK_BLOCKS) * 256 + threadIdx.x;
    if (i >= N_NODES * HDIM / 4) return;
    float4 v = reinterpret_cast<const float4*>(hv)[i];
    half2v o0, o1;
    o0[0] = (_Float16)v.x; o0[1] = (_Float16)v.y;
    o1[0] = (_Float16)v.z; o1[1] = (_Float16)v.w;
    reinterpret_cast<half2v*>(hvh)[i * 2] = o0;
    reinterpret_cast<half2v*>(hvh)[i * 2 + 1] = o1;
    return;
  }
  int g = blockIdx.x * 256 + threadIdx.x;
  if (g < TROUNDS * 256) {
    int t = g >> 8, j = g & 255;
    we[g] = Wmsg[((size_t)t * 256 + j) * 257 + 256];
  }
  int t = g / PACK_PER_T;
  int r = g % PACK_PER_T;
  int lane = r & 63;
  int fr = r >> 6;  // 0..415
  const float* srcp;
  _Float16* dstp;
  if (fr < 128) {
    int jt = fr >> 3, kt = fr & 7;
    int j = jt * 16 + (lane & 15);
    int k = kt * 32 + ((lane >> 4) << 3);
    srcp = Wmsg + (size_t)t * 256 * 257 + (size_t)j * 257 + k;
    dstp = W1p + ((size_t)t * 128 + fr) * 512 + lane * 8;
  } else {
    int fr2 = fr - 128;  // 0..287
    int chunk = fr2 / 12, idx = fr2 % 12;
    int jt = chunk / 3, pp = chunk % 3;
    int j = pp * 128 + jt * 16 + (lane & 15);
    int k;
    if (idx < 8) {
      k = idx * 32 + ((lane >> 4) << 3);
      srcp = Wih + (size_t)t * 384 * 256 + (size_t)j * 256 + k;
    } else {
      k = (idx - 8) * 32 + ((lane >> 4) << 3);
      srcp = Whh + (size_t)t * 384 * 128 + (size_t)j * 128 + k;
    }
    dstp = W2p + ((size_t)t * 288 + fr2) * 512 + lane * 8;
  }
  #pragma unroll
  for (int e = 0; e < 8; ++e) dstp[e] = (_Float16)srcp[e];
}

// ---- phase 1: bucket edges by dst>>8; record = (dst<<32)|(he16<<16)|src ----
__global__ __launch_bounds__(256) void bin_count(
    const int* __restrict__ src, const int* __restrict__ dst,
    const float* __restrict__ he, int* __restrict__ bcur, u64* __restrict__ barr) {
  __shared__ int hist[256];
  __shared__ int incl[256];
  __shared__ int cur[256];
  __shared__ int gbase[256];
  __shared__ u64 staged[BCE];  // 16 KB
  const int tid = threadIdx.x;
  const int e0 = blockIdx.x * BCE;
  const int tot = min(BCE, N_EDGES - e0);

  hist[tid] = 0;
  __syncthreads();

  u64 rec[BCE / 256];
  int nmine = 0;
  #pragma unroll
  for (int q = 0; q < BCE / 256; ++q) {
    int e = e0 + q * 256 + tid;
    if (e < N_EDGES) {
      uint32_t d = (uint32_t)dst[e];
      uint32_t s = (uint32_t)src[e];
      _Float16 hh = (_Float16)he[e];
      ushort_t hb;
      __builtin_memcpy(&hb, &hh, 2);
      rec[nmine] = ((u64)d << 32) | ((u64)hb << 16) | (u64)s;
      atomicAdd(&hist[d >> 8], 1);
      ++nmine;
    }
  }
  __syncthreads();

  incl[tid] = hist[tid];
  __syncthreads();
  for (int off = 1; off < 256; off <<= 1) {
    int v = incl[tid];
    int a = (tid >= off) ? incl[tid - off] : 0;
    __syncthreads();
    incl[tid] = v + a;
    __syncthreads();
  }
  cur[tid] = incl[tid] - hist[tid];
  __syncthreads();

  for (int q = 0; q < nmine; ++q) {
    int b = (int)(rec[q] >> 40);
    int pos = atomicAdd(&cur[b], 1);
    staged[pos] = rec[q];
  }
  if (tid < NBUK && hist[tid] > 0) gbase[tid] = atomicAdd(&bcur[tid], hist[tid]);
  __syncthreads();

  for (int i = tid; i < tot; i += 256) {
    u64 r = staged[i];
    int b = (int)(r >> 40);
    int excl = incl[b] - hist[b];
    barr[(size_t)b * BCAP + gbase[b] + (i - excl)] = r;
  }
}

// ---- phase 2: one block per bucket; bin into padded CSR rows + deg ----
__global__ __launch_bounds__(256) void bin_place(
    const int* __restrict__ bcur, const u64* __restrict__ barr,
    uint32_t* __restrict__ csr, int* __restrict__ deg_i) {
  __shared__ int lcnt[256];
  const int b = blockIdx.x;
  const int tid = threadIdx.x;
  const int cnt = bcur[b];
  lcnt[tid] = 0;
  __syncthreads();
  const u64* bp = barr + (size_t)b * BCAP;
  for (int i = tid; i < cnt; i += 256) {
    u64 r = bp[i];
    int d = (int)((r >> 32) & 0xffffu);
    int slot = atomicAdd(&lcnt[d & 255], 1);
    if (slot < MAXDEG) csr[(size_t)d * MAXDEG + slot] = (uint32_t)r;
  }
  __syncthreads();
  int node = b * 256 + tid;
  if (node < N_NODES) deg_i[node] = min(lcnt[tid], MAXDEG);
}

// one wave per node: S_h[v] = fp16(sum hvh[src]); hsum[v] = sum he; deg_f[v] = deg
__global__ void gather_h(const _Float16* __restrict__ hvh, const int* __restrict__ deg_i,
                         const uint32_t* __restrict__ csr, _Float16* __restrict__ S_h,
                         float* __restrict__ hsum, float* __restrict__ deg_f, int n) {
  int wid = (int)((blockIdx.x * blockDim.x + threadIdx.x) >> 6);
  int lane = threadIdx.x & 63;
  if (wid >= n) return;
  int deg = deg_i[wid];
  uint32_t ent = (lane < deg) ? csr[(size_t)wid * MAXDEG + lane] : 0u;
  float a0 = 0.f, a1 = 0.f, hs = 0.f;
  int k = 0;
  for (; k + 7 < deg; k += 8) {
    uint32_t ee[8];
    #pragma unroll
    for (int q = 0; q < 8; ++q) ee[q] = __shfl(ent, k + q);
    half2v vv[8];
    #pragma unroll
    for (int q = 0; q < 8; ++q)
      vv[q] = *reinterpret_cast<const half2v*>(hvh + (size_t)(ee[q] & 0xffffu) * HDIM + lane * 2);
    #pragma unroll
    for (int q = 0; q < 8; ++q) {
      a0 += (float)vv[q][0];
      a1 += (float)vv[q][1];
      hs += f16bits2f(ee[q] >> 16);
    }
  }
  for (; k < deg; ++k) {
    uint32_t e0 = __shfl(ent, k);
    half2v v0 = *reinterpret_cast<const half2v*>(hvh + (size_t)(e0 & 0xffffu) * HDIM + lane * 2);
    a0 += (float)v0[0];
    a1 += (float)v0[1];
    hs += f16bits2f(e0 >> 16);
  }
  half2v o;
  o[0] = (_Float16)a0;
  o[1] = (_Float16)a1;
  *reinterpret_cast<half2v*>(S_h + (size_t)wid * HDIM + lane * 2) = o;
  if (lane == 0) hsum[wid] = hs;
  if (lane == 1) deg_f[wid] = (float)deg;
}

// ---------------- U1: a = (deg.hv | S) * W1^T + deg*bmsg + hsum*we ----------------
// 8 phases x 16 KB (2 jt/phase); 2 buffers (32 KB); barriers halved, occupancy kept.
__global__ __launch_bounds__(256, 4) void u1_kernel(
    const _Float16* __restrict__ hvh, const _Float16* __restrict__ S_h,
    const float* __restrict__ deg_f, const float* __restrict__ hsum,
    const _Float16* __restrict__ W1p, const float* __restrict__ we,
    const float* __restrict__ bmsg, _Float16* __restrict__ a_out) {
  __shared__ _Float16 buf[2][16 * 512];  // 2 x 16 KB
  const int tid = threadIdx.x;
  const int wv = tid >> 6, lane = tid & 63;
  const int tile = blockIdx.x * 4 + wv;
  const bool act = (tile < NTILES);
  const int rowA = tile * 16 + (lane & 15);
  const int koff = (lane >> 4) * 8;
  const int m0 = (lane >> 4) * 4;

  // stage phase ph: 16 KB = chunks {2ph, 2ph+1}; wave wv stages rows wv*4..wv*4+3
  auto stage = [&](int ph) {
    const _Float16* g = W1p + (size_t)ph * 8192 + (size_t)(wv * 4) * 512 + lane * 8;
    _Float16* l = &buf[ph & 1][(wv * 4) * 512];
    #pragma unroll
    for (int i = 0; i < 4; ++i) GLD_LDS(g + i * 512, l + i * 512);
  };
  stage(0);

  half8v x[8];
  float degs[4], hss[4];
  if (act) {
    float deg = deg_f[rowA];
    const _Float16* hrow = hvh + (size_t)rowA * HDIM + koff;
    #pragma unroll
    for (int kt = 0; kt < 4; ++kt) {
      half8v hvv = *reinterpret_cast<const half8v*>(hrow + kt * 32);
      #pragma unroll
      for (int e = 0; e < 8; ++e) x[kt][e] = (_Float16)((float)hvv[e] * deg);
    }
    const _Float16* srow = S_h + (size_t)rowA * HDIM + koff;
    #pragma unroll
    for (int kt = 0; kt < 4; ++kt)
      x[4 + kt] = *reinterpret_cast<const half8v*>(srow + kt * 32);
    #pragma unroll
    for (int rr = 0; rr < 4; ++rr) {
      degs[rr] = deg_f[tile * 16 + m0 + rr];
      hss[rr] = hsum[tile * 16 + m0 + rr];
    }
  }

  #pragma unroll 1
  for (int ph = 0; ph < 8; ++ph) {
    __syncthreads();  // drains phase-ph DMA + frees buf[(ph+1)&1]
    if (ph < 7) stage(ph + 1);
    #pragma unroll
    for (int half = 0; half < 2; ++half) {
      const _Float16* B = &buf[ph & 1][(size_t)half * 8 * 512];
      f32x4 acc = {0.f, 0.f, 0.f, 0.f};
      #pragma unroll
      for (int kt = 0; kt < 8; ++kt) {
        half8v b = *reinterpret_cast<const half8v*>(B + (size_t)kt * 512 + lane * 8);
        acc = __builtin_amdgcn_mfma_f32_16x16x32_f16(x[kt], b, acc, 0, 0, 0);
      }
      if (act) {
        int jt = ph * 2 + half;
        int j = jt * 16 + (lane & 15);
        float bm = bmsg[j], w = we[j];
        #pragma unroll
        for (int rr = 0; rr < 4; ++rr)
          a_out[(size_t)(tile * 16 + m0 + rr) * 256 + j] =
              (_Float16)(acc[rr] + degs[rr] * bm + hss[rr] * w);
      }
    }
  }
}

// ---------------- U2: gi = a*Wih^T, gh = hv*Whh^T, GRU gates ----------------
// 12 phases x 24 KB (2 gate-chunks/phase); 2 buffers (48 KB), LB(256,3).
__global__ __launch_bounds__(256, 3) void u2_kernel(
    const _Float16* __restrict__ a_in, const _Float16* __restrict__ hvh_in,
    const _Float16* __restrict__ W2p, const float* __restrict__ bih,
    const float* __restrict__ bhh, float* __restrict__ hv_out,
    _Float16* __restrict__ hvh_out) {
  __shared__ _Float16 buf[2][24 * 512];  // 2 x 24 KB
  const int tid = threadIdx.x;
  const int wv = tid >> 6, lane = tid & 63;
  const int tile = blockIdx.x * 4 + wv;
  const bool act = (tile < NTILES);
  const int rowA = tile * 16 + (lane & 15);
  const int koff = (lane >> 4) * 8;
  const int m0 = (lane >> 4) * 4;

  // stage phase ph: 24 KB = chunks {2ph, 2ph+1}; wave wv stages rows wv*6..wv*6+5
  auto stage = [&](int ph) {
    const _Float16* g = W2p + (size_t)ph * 12288 + (size_t)(wv * 6) * 512 + lane * 8;
    _Float16* l = &buf[ph & 1][(wv * 6) * 512];
    #pragma unroll
    for (int i = 0; i < 6; ++i) GLD_LDS(g + i * 512, l + i * 512);
  };
  stage(0);

  half8v a8[8], h4[4];
  if (act) {
    const _Float16* ar = a_in + (size_t)rowA * 256 + koff;
    #pragma unroll
    for (int kt = 0; kt < 8; ++kt)
      a8[kt] = *reinterpret_cast<const half8v*>(ar + kt * 32);
    const _Float16* hr = hvh_in + (size_t)rowA * HDIM + koff;
    #pragma unroll
    for (int kt = 0; kt < 4; ++kt)
      h4[kt] = *reinterpret_cast<const half8v*>(hr + kt * 32);
  }

  auto compute = [&](const _Float16* B, f32x4& ai, f32x4& ag) {
    ai = (f32x4){0.f, 0.f, 0.f, 0.f};
    ag = (f32x4){0.f, 0.f, 0.f, 0.f};
    #pragma unroll
    for (int kt = 0; kt < 8; ++kt) {
      half8v b = *reinterpret_cast<const half8v*>(B + (size_t)kt * 512 + lane * 8);
      ai = __builtin_amdgcn_mfma_f32_16x16x32_f16(a8[kt], b, ai, 0, 0, 0);
    }
    #pragma unroll
    for (int kt = 0; kt < 4; ++kt) {
      half8v b = *reinterpret_cast<const half8v*>(B + (size_t)(8 + kt) * 512 + lane * 8);
      ag = __builtin_amdgcn_mfma_f32_16x16x32_f16(h4[kt], b, ag, 0, 0, 0);
    }
  };

  f32x4 rreg, zreg, ai, ag;
  #pragma unroll 1
  for (int ph = 0; ph < 12; ++ph) {
    __syncthreads();  // drains phase-ph DMA + frees buf[(ph+1)&1]
    if (ph < 11) stage(ph + 1);
    #pragma unroll
    for (int half = 0; half < 2; ++half) {
      const int c = ph * 2 + half;      // gate-chunk index 0..23
      const int jt = c / 3, p = c % 3;
      const int fcol = jt * 16 + (lane & 15);
      compute(&buf[ph & 1][(size_t)half * 12 * 512], ai, ag);
      if (act) {
        if (p == 0) {
          float bi = bih[fcol], bq = bhh[fcol];
          #pragma unroll
          for (int rr = 0; rr < 4; ++rr) rreg[rr] = sigmoidf_(ai[rr] + bi + ag[rr] + bq);
        } else if (p == 1) {
          float bi = bih[128 + fcol], bq = bhh[128 + fcol];
          #pragma unroll
          for (int rr = 0; rr < 4; ++rr) zreg[rr] = sigmoidf_(ai[rr] + bi + ag[rr] + bq);
        } else {
          float bi = bih[256 + fcol], bq = bhh[256 + fcol];
          #pragma unroll
          for (int rr = 0; rr < 4; ++rr) {
            int node = tile * 16 + m0 + rr;
            float n = tanhf_(ai[rr] + bi + rreg[rr] * (ag[rr] + bq));
            float h = (float)hvh_in[(size_t)node * HDIM + fcol];
            float hn = (1.f - zreg[rr]) * n + zreg[rr] * h;
            if (hv_out) hv_out[(size_t)node * HDIM + fcol] = hn;
            if (hvh_out) hvh_out[(size_t)node * HDIM + fcol] = (_Float16)hn;
          }
        }
      }
    }
  }
}

extern "C" void kernel_launch(void* const* d_in, const int* in_sizes, int n_in,
                              void* d_out, int out_size, void* d_ws, size_t ws_size,
                              hipStream_t stream) {
  const float* hv   = (const float*)d_in[0];
  const float* he   = (const float*)d_in[1];
  const int*   src  = (const int*)d_in[2];
  const int*   dst  = (const int*)d_in[3];
  const float* Wmsg = (const float*)d_in[4];
  const float* bmsg = (const float*)d_in[5];
  const float* Wih  = (const float*)d_in[6];
  const float* Whh  = (const float*)d_in[7];
  const float* bih  = (const float*)d_in[8];
  const float* bhh  = (const float*)d_in[9];

  char* p = (char*)d_ws;
  auto alloc = [&](size_t bytes) { char* r = p; p += (bytes + 255) & ~(size_t)255; return r; };
  _Float16* S_h   = (_Float16*)alloc((size_t)N_NODES * HDIM * 2);
  _Float16* a_buf = (_Float16*)alloc((size_t)N_NODES * 256 * 2);
  _Float16* hvh   = (_Float16*)alloc((size_t)N_NODES * HDIM * 2);
  float*    deg_f = (float*)alloc((size_t)N_NODES * 4);
  float*    hsum  = (float*)alloc((size_t)N_NODES * 4);
  float*    we    = (float*)alloc((size_t)TROUNDS * 256 * 4);
  const size_t W1PT = (size_t)128 * 512;  // per-round halves (128 KB)
  const size_t W2PT = (size_t)288 * 512;  // per-round halves (288 KB)
  _Float16* W1p = (_Float16*)alloc(TROUNDS * W1PT * 2);
  _Float16* W2p = (_Float16*)alloc(TROUNDS * W2PT * 2);
  int*      deg_i = (int*)alloc((size_t)N_NODES * 4);
  int*      bcur  = (int*)alloc((size_t)NBUK * 4);
  u64*      barr  = (u64*)alloc((size_t)NBUK * BCAP * 8);
  uint32_t* csr   = (uint32_t*)alloc((size_t)N_NODES * MAXDEG * 4);

  pack_cast<<<PACK_BLOCKS + CAST_BLOCKS, 256, 0, stream>>>(
      Wmsg, Wih, Whh, hv, W1p, W2p, we, hvh, bcur);
  bin_count<<<NBC, 256, 0, stream>>>(src, dst, he, bcur, barr);
  bin_place<<<NBUK, 256, 0, stream>>>(bcur, barr, csr, deg_i);

  float* outp = (float*)d_out;
  const int ugrid = (NTILES + 3) / 4;  // 782
  for (int t = 0; t < TROUNDS; ++t) {
    gather_h<<<(N_NODES + 3) / 4, 256, 0, stream>>>(hvh, deg_i, csr, S_h, hsum, deg_f, N_NODES);
    u1_kernel<<<ugrid, 256, 0, stream>>>(
        hvh, S_h, deg_f, hsum, W1p + (size_t)t * W1PT,
        we + (size_t)t * 256, bmsg + (size_t)t * 256, a_buf);
    u2_kernel<<<ugrid, 256, 0, stream>>>(
        a_buf, hvh, W2p + (size_t)t * W2PT,
        bih + (size_t)t * 384, bhh + (size_t)t * 384,
        (t == TROUNDS - 1) ? outp : (float*)nullptr,
        (t < TROUNDS - 1) ? hvh : (_Float16*)nullptr);
  }
  (void)in_sizes; (void)n_in; (void)out_size; (void)ws_size;
}

// Round 19
// 205.542 us; speedup vs baseline: 1.1430x; 1.1430x over previous
//
#include <hip/hip_runtime.h>
#include <cstdint>
#include <cstddef>

#define N_NODES 50000
#define N_EDGES 800000
#define HDIM 128
#define TROUNDS 2
#define NTILES 3125
#define PACK_PER_T (416 * 64)   // 128 W1 frag-rows + 288 W2 frag-rows
#define PACK_BLOCKS ((TROUNDS * PACK_PER_T) / 256)  // 208
#define CAST_BLOCKS ((N_NODES * HDIM / 4 + 255) / 256)  // 6250
#define MAXDEG 64
#define NBUK 196                // buckets of 256 node-ids (dst >> 8)
#define BCAP 4608               // per-bucket capacity (mean 4082, +8 sigma)
#define BCE 2048                // edges per bin_count block
#define NBC ((N_EDGES + BCE - 1) / BCE)  // 391

typedef __attribute__((ext_vector_type(8))) _Float16 half8v;
typedef __attribute__((ext_vector_type(2))) _Float16 half2v;
typedef __attribute__((ext_vector_type(4))) float f32x4;
typedef unsigned short ushort_t;
typedef unsigned long long u64;

#define GLD_LDS(gp, lp)                                                        \
  __builtin_amdgcn_global_load_lds(                                            \
      (__attribute__((address_space(1))) const void*)(gp),                     \
      (__attribute__((address_space(3))) void*)(lp), 16, 0, 0)

static __device__ __forceinline__ float sigmoidf_(float x) {
  return 1.0f / (1.0f + __expf(-x));
}
static __device__ __forceinline__ float tanhf_(float x) {
  float xc = fminf(15.0f, fmaxf(-15.0f, x));
  float a = __expf(2.0f * xc);
  return (a - 1.0f) / (a + 1.0f);
}
static __device__ __forceinline__ float f16bits2f(uint32_t hb) {
  ushort_t u = (ushort_t)hb;
  _Float16 h;
  __builtin_memcpy(&h, &u, 2);
  return (float)h;
}

// ---------------- one-shot setup: weight pack + hv fp16 cast + bcur zero ----------------
// W1p[t][jt(16)][kt(8)][lane][8]  fp16, chunk/jt = 8 KB
// W2p[t][chunk(24)=jt*3+p][idx(12)][lane][8] fp16, chunk = 12 KB
__global__ void pack_cast(const float* __restrict__ Wmsg, const float* __restrict__ Wih,
                          const float* __restrict__ Whh, const float* __restrict__ hv,
                          _Float16* __restrict__ W1p, _Float16* __restrict__ W2p,
                          float* __restrict__ we, _Float16* __restrict__ hvh,
                          int* __restrict__ bcur) {
  if (blockIdx.x == 0 && threadIdx.x < NBUK) bcur[threadIdx.x] = 0;
  if (blockIdx.x >= PACK_BLOCKS) {
    int i = (blockIdx.x - PACK_BLOCKS) * 256 + threadIdx.x;
    if (i >= N_NODES * HDIM / 4) return;
    float4 v = reinterpret_cast<const float4*>(hv)[i];
    half2v o0, o1;
    o0[0] = (_Float16)v.x; o0[1] = (_Float16)v.y;
    o1[0] = (_Float16)v.z; o1[1] = (_Float16)v.w;
    reinterpret_cast<half2v*>(hvh)[i * 2] = o0;
    reinterpret_cast<half2v*>(hvh)[i * 2 + 1] = o1;
    return;
  }
  int g = blockIdx.x * 256 + threadIdx.x;
  if (g < TROUNDS * 256) {
    int t = g >> 8, j = g & 255;
    we[g] = Wmsg[((size_t)t * 256 + j) * 257 + 256];
  }
  int t = g / PACK_PER_T;
  int r = g % PACK_PER_T;
  int lane = r & 63;
  int fr = r >> 6;  // 0..415
  const float* srcp;
  _Float16* dstp;
  if (fr < 128) {
    int jt = fr >> 3, kt = fr & 7;
    int j = jt * 16 + (lane & 15);
    int k = kt * 32 + ((lane >> 4) << 3);
    srcp = Wmsg + (size_t)t * 256 * 257 + (size_t)j * 257 + k;
    dstp = W1p + ((size_t)t * 128 + fr) * 512 + lane * 8;
  } else {
    int fr2 = fr - 128;  // 0..287
    int chunk = fr2 / 12, idx = fr2 % 12;
    int jt = chunk / 3, pp = chunk % 3;
    int j = pp * 128 + jt * 16 + (lane & 15);
    int k;
    if (idx < 8) {
      k = idx * 32 + ((lane >> 4) << 3);
      srcp = Wih + (size_t)t * 384 * 256 + (size_t)j * 256 + k;
    } else {
      k = (idx - 8) * 32 + ((lane >> 4) << 3);
      srcp = Whh + (size_t)t * 384 * 128 + (size_t)j * 128 + k;
    }
    dstp = W2p + ((size_t)t * 288 + fr2) * 512 + lane * 8;
  }
  #pragma unroll
  for (int e = 0; e < 8; ++e) dstp[e] = (_Float16)srcp[e];
}

// ---- phase 1: bucket edges by dst>>8; record = (dst<<32)|(he16<<16)|src ----
__global__ __launch_bounds__(256) void bin_count(
    const int* __restrict__ src, const int* __restrict__ dst,
    const float* __restrict__ he, int* __restrict__ bcur, u64* __restrict__ barr) {
  __shared__ int hist[256];
  __shared__ int incl[256];
  __shared__ int cur[256];
  __shared__ int gbase[256];
  __shared__ u64 staged[BCE];  // 16 KB
  const int tid = threadIdx.x;
  const int e0 = blockIdx.x * BCE;
  const int tot = min(BCE, N_EDGES - e0);

  hist[tid] = 0;
  __syncthreads();

  u64 rec[BCE / 256];
  int nmine = 0;
  #pragma unroll
  for (int q = 0; q < BCE / 256; ++q) {
    int e = e0 + q * 256 + tid;
    if (e < N_EDGES) {
      uint32_t d = (uint32_t)dst[e];
      uint32_t s = (uint32_t)src[e];
      _Float16 hh = (_Float16)he[e];
      ushort_t hb;
      __builtin_memcpy(&hb, &hh, 2);
      rec[nmine] = ((u64)d << 32) | ((u64)hb << 16) | (u64)s;
      atomicAdd(&hist[d >> 8], 1);
      ++nmine;
    }
  }
  __syncthreads();

  incl[tid] = hist[tid];
  __syncthreads();
  for (int off = 1; off < 256; off <<= 1) {
    int v = incl[tid];
    int a = (tid >= off) ? incl[tid - off] : 0;
    __syncthreads();
    incl[tid] = v + a;
    __syncthreads();
  }
  cur[tid] = incl[tid] - hist[tid];
  __syncthreads();

  for (int q = 0; q < nmine; ++q) {
    int b = (int)(rec[q] >> 40);
    int pos = atomicAdd(&cur[b], 1);
    staged[pos] = rec[q];
  }
  if (tid < NBUK && hist[tid] > 0) gbase[tid] = atomicAdd(&bcur[tid], hist[tid]);
  __syncthreads();

  for (int i = tid; i < tot; i += 256) {
    u64 r = staged[i];
    int b = (int)(r >> 40);
    int excl = incl[b] - hist[b];
    barr[(size_t)b * BCAP + gbase[b] + (i - excl)] = r;
  }
}

// ---- phase 2: one block per bucket; bin into padded CSR rows + deg ----
__global__ __launch_bounds__(256) void bin_place(
    const int* __restrict__ bcur, const u64* __restrict__ barr,
    uint32_t* __restrict__ csr, int* __restrict__ deg_i) {
  __shared__ int lcnt[256];
  const int b = blockIdx.x;
  const int tid = threadIdx.x;
  const int cnt = bcur[b];
  lcnt[tid] = 0;
  __syncthreads();
  const u64* bp = barr + (size_t)b * BCAP;
  for (int i = tid; i < cnt; i += 256) {
    u64 r = bp[i];
    int d = (int)((r >> 32) & 0xffffu);
    int slot = atomicAdd(&lcnt[d & 255], 1);
    if (slot < MAXDEG) csr[(size_t)d * MAXDEG + slot] = (uint32_t)r;
  }
  __syncthreads();
  int node = b * 256 + tid;
  if (node < N_NODES) deg_i[node] = min(lcnt[tid], MAXDEG);
}

// one wave per node: S_h[v] = fp16(sum hvh[src]); hsum[v] = sum he; deg_f[v] = deg
__global__ void gather_h(const _Float16* __restrict__ hvh, const int* __restrict__ deg_i,
                         const uint32_t* __restrict__ csr, _Float16* __restrict__ S_h,
                         float* __restrict__ hsum, float* __restrict__ deg_f, int n) {
  int wid = (int)((blockIdx.x * blockDim.x + threadIdx.x) >> 6);
  int lane = threadIdx.x & 63;
  if (wid >= n) return;
  int deg = deg_i[wid];
  uint32_t ent = (lane < deg) ? csr[(size_t)wid * MAXDEG + lane] : 0u;
  float a0 = 0.f, a1 = 0.f, hs = 0.f;
  int k = 0;
  for (; k + 7 < deg; k += 8) {
    uint32_t ee[8];
    #pragma unroll
    for (int q = 0; q < 8; ++q) ee[q] = __shfl(ent, k + q);
    half2v vv[8];
    #pragma unroll
    for (int q = 0; q < 8; ++q)
      vv[q] = *reinterpret_cast<const half2v*>(hvh + (size_t)(ee[q] & 0xffffu) * HDIM + lane * 2);
    #pragma unroll
    for (int q = 0; q < 8; ++q) {
      a0 += (float)vv[q][0];
      a1 += (float)vv[q][1];
      hs += f16bits2f(ee[q] >> 16);
    }
  }
  for (; k < deg; ++k) {
    uint32_t e0 = __shfl(ent, k);
    half2v v0 = *reinterpret_cast<const half2v*>(hvh + (size_t)(e0 & 0xffffu) * HDIM + lane * 2);
    a0 += (float)v0[0];
    a1 += (float)v0[1];
    hs += f16bits2f(e0 >> 16);
  }
  half2v o;
  o[0] = (_Float16)a0;
  o[1] = (_Float16)a1;
  *reinterpret_cast<half2v*>(S_h + (size_t)wid * HDIM + lane * 2) = o;
  if (lane == 0) hsum[wid] = hs;
  if (lane == 1) deg_f[wid] = (float)deg;
}

// ---------------- U1: a = (deg.hv | S) * W1^T + deg*bmsg + hsum*we ----------------
// 8 phases x 16 KB (2 jt/phase); 2 buffers (32 KB); LB(256,4) — full occupancy.
__global__ __launch_bounds__(256, 4) void u1_kernel(
    const _Float16* __restrict__ hvh, const _Float16* __restrict__ S_h,
    const float* __restrict__ deg_f, const float* __restrict__ hsum,
    const _Float16* __restrict__ W1p, const float* __restrict__ we,
    const float* __restrict__ bmsg, _Float16* __restrict__ a_out) {
  __shared__ _Float16 buf[2][16 * 512];  // 2 x 16 KB
  const int tid = threadIdx.x;
  const int wv = tid >> 6, lane = tid & 63;
  const int tile = blockIdx.x * 4 + wv;
  const bool act = (tile < NTILES);
  const int rowA = tile * 16 + (lane & 15);
  const int koff = (lane >> 4) * 8;
  const int m0 = (lane >> 4) * 4;

  auto stage = [&](int ph) {
    const _Float16* g = W1p + (size_t)ph * 8192 + (size_t)(wv * 4) * 512 + lane * 8;
    _Float16* l = &buf[ph & 1][(wv * 4) * 512];
    #pragma unroll
    for (int i = 0; i < 4; ++i) GLD_LDS(g + i * 512, l + i * 512);
  };
  stage(0);

  half8v x[8];
  float degs[4], hss[4];
  if (act) {
    float deg = deg_f[rowA];
    const _Float16* hrow = hvh + (size_t)rowA * HDIM + koff;
    #pragma unroll
    for (int kt = 0; kt < 4; ++kt) {
      half8v hvv = *reinterpret_cast<const half8v*>(hrow + kt * 32);
      #pragma unroll
      for (int e = 0; e < 8; ++e) x[kt][e] = (_Float16)((float)hvv[e] * deg);
    }
    const _Float16* srow = S_h + (size_t)rowA * HDIM + koff;
    #pragma unroll
    for (int kt = 0; kt < 4; ++kt)
      x[4 + kt] = *reinterpret_cast<const half8v*>(srow + kt * 32);
    #pragma unroll
    for (int rr = 0; rr < 4; ++rr) {
      degs[rr] = deg_f[tile * 16 + m0 + rr];
      hss[rr] = hsum[tile * 16 + m0 + rr];
    }
  }

  #pragma unroll 1
  for (int ph = 0; ph < 8; ++ph) {
    __syncthreads();
    if (ph < 7) stage(ph + 1);
    #pragma unroll
    for (int half = 0; half < 2; ++half) {
      const _Float16* B = &buf[ph & 1][(size_t)half * 8 * 512];
      f32x4 acc = {0.f, 0.f, 0.f, 0.f};
      #pragma unroll
      for (int kt = 0; kt < 8; ++kt) {
        half8v b = *reinterpret_cast<const half8v*>(B + (size_t)kt * 512 + lane * 8);
        acc = __builtin_amdgcn_mfma_f32_16x16x32_f16(x[kt], b, acc, 0, 0, 0);
      }
      if (act) {
        int jt = ph * 2 + half;
        int j = jt * 16 + (lane & 15);
        float bm = bmsg[j], w = we[j];
        #pragma unroll
        for (int rr = 0; rr < 4; ++rr)
          a_out[(size_t)(tile * 16 + m0 + rr) * 256 + j] =
              (_Float16)(acc[rr] + degs[rr] * bm + hss[rr] * w);
      }
    }
  }
}

// ---------------- U2: gi = a*Wih^T, gh = hv*Whh^T, GRU gates ----------------
// R17 structure: 24 phases x 12 KB, 2 buffers (24 KB), LB(256,4).
__global__ __launch_bounds__(256, 4) void u2_kernel(
    const _Float16* __restrict__ a_in, const _Float16* __restrict__ hvh_in,
    const _Float16* __restrict__ W2p, const float* __restrict__ bih,
    const float* __restrict__ bhh, float* __restrict__ hv_out,
    _Float16* __restrict__ hvh_out) {
  __shared__ _Float16 buf[2][12 * 512];  // 2 x 12 KB
  const int tid = threadIdx.x;
  const int wv = tid >> 6, lane = tid & 63;
  const int tile = blockIdx.x * 4 + wv;
  const bool act = (tile < NTILES);
  const int rowA = tile * 16 + (lane & 15);
  const int koff = (lane >> 4) * 8;
  const int m0 = (lane >> 4) * 4;

  auto stage = [&](int n) {
    const _Float16* g = W2p + (size_t)n * 6144 + (size_t)(wv * 3) * 512 + lane * 8;
    _Float16* l = &buf[n & 1][(wv * 3) * 512];
    #pragma unroll
    for (int i = 0; i < 3; ++i) GLD_LDS(g + i * 512, l + i * 512);
  };

  stage(0);

  half8v a8[8], h4[4];
  if (act) {
    const _Float16* ar = a_in + (size_t)rowA * 256 + koff;
    #pragma unroll
    for (int kt = 0; kt < 8; ++kt)
      a8[kt] = *reinterpret_cast<const half8v*>(ar + kt * 32);
    const _Float16* hr = hvh_in + (size_t)rowA * HDIM + koff;
    #pragma unroll
    for (int kt = 0; kt < 4; ++kt)
      h4[kt] = *reinterpret_cast<const half8v*>(hr + kt * 32);
  }

  auto compute = [&](const _Float16* B, f32x4& ai, f32x4& ag) {
    ai = (f32x4){0.f, 0.f, 0.f, 0.f};
    ag = (f32x4){0.f, 0.f, 0.f, 0.f};
    #pragma unroll
    for (int kt = 0; kt < 8; ++kt) {
      half8v b = *reinterpret_cast<const half8v*>(B + (size_t)kt * 512 + lane * 8);
      ai = __builtin_amdgcn_mfma_f32_16x16x32_f16(a8[kt], b, ai, 0, 0, 0);
    }
    #pragma unroll
    for (int kt = 0; kt < 4; ++kt) {
      half8v b = *reinterpret_cast<const half8v*>(B + (size_t)(8 + kt) * 512 + lane * 8);
      ag = __builtin_amdgcn_mfma_f32_16x16x32_f16(h4[kt], b, ag, 0, 0, 0);
    }
  };

  f32x4 rreg, zreg, ai, ag;
  #pragma unroll 1
  for (int jt = 0; jt < 8; ++jt) {
    const int c0 = jt * 3;
    const int fcol = jt * 16 + (lane & 15);
    // p = 0 : reset gate r
    __syncthreads();
    stage(c0 + 1);
    compute(&buf[c0 & 1][0], ai, ag);
    if (act) {
      float bi = bih[fcol], bq = bhh[fcol];
      #pragma unroll
      for (int rr = 0; rr < 4; ++rr) rreg[rr] = sigmoidf_(ai[rr] + bi + ag[rr] + bq);
    }
    // p = 1 : update gate z
    __syncthreads();
    stage(c0 + 2);
    compute(&buf[(c0 + 1) & 1][0], ai, ag);
    if (act) {
      float bi = bih[128 + fcol], bq = bhh[128 + fcol];
      #pragma unroll
      for (int rr = 0; rr < 4; ++rr) zreg[rr] = sigmoidf_(ai[rr] + bi + ag[rr] + bq);
    }
    // p = 2 : candidate n + output
    __syncthreads();
    if (jt < 7) stage(c0 + 3);
    compute(&buf[(c0 + 2) & 1][0], ai, ag);
    if (act) {
      float bi = bih[256 + fcol], bq = bhh[256 + fcol];
      #pragma unroll
      for (int rr = 0; rr < 4; ++rr) {
        int node = tile * 16 + m0 + rr;
        float n = tanhf_(ai[rr] + bi + rreg[rr] * (ag[rr] + bq));
        float h = (float)hvh_in[(size_t)node * HDIM + fcol];
        float hn = (1.f - zreg[rr]) * n + zreg[rr] * h;
        if (hv_out) hv_out[(size_t)node * HDIM + fcol] = hn;
        if (hvh_out) hvh_out[(size_t)node * HDIM + fcol] = (_Float16)hn;
      }
    }
  }
}

extern "C" void kernel_launch(void* const* d_in, const int* in_sizes, int n_in,
                              void* d_out, int out_size, void* d_ws, size_t ws_size,
                              hipStream_t stream) {
  const float* hv   = (const float*)d_in[0];
  const float* he   = (const float*)d_in[1];
  const int*   src  = (const int*)d_in[2];
  const int*   dst  = (const int*)d_in[3];
  const float* Wmsg = (const float*)d_in[4];
  const float* bmsg = (const float*)d_in[5];
  const float* Wih  = (const float*)d_in[6];
  const float* Whh  = (const float*)d_in[7];
  const float* bih  = (const float*)d_in[8];
  const float* bhh  = (const float*)d_in[9];

  char* p = (char*)d_ws;
  auto alloc = [&](size_t bytes) { char* r = p; p += (bytes + 255) & ~(size_t)255; return r; };
  _Float16* S_h   = (_Float16*)alloc((size_t)N_NODES * HDIM * 2);
  _Float16* a_buf = (_Float16*)alloc((size_t)N_NODES * 256 * 2);
  _Float16* hvh   = (_Float16*)alloc((size_t)N_NODES * HDIM * 2);
  float*    deg_f = (float*)alloc((size_t)N_NODES * 4);
  float*    hsum  = (float*)alloc((size_t)N_NODES * 4);
  float*    we    = (float*)alloc((size_t)TROUNDS * 256 * 4);
  const size_t W1PT = (size_t)128 * 512;  // per-round halves (128 KB)
  const size_t W2PT = (size_t)288 * 512;  // per-round halves (288 KB)
  _Float16* W1p = (_Float16*)alloc(TROUNDS * W1PT * 2);
  _Float16* W2p = (_Float16*)alloc(TROUNDS * W2PT * 2);
  int*      deg_i = (int*)alloc((size_t)N_NODES * 4);
  int*      bcur  = (int*)alloc((size_t)NBUK * 4);
  u64*      barr  = (u64*)alloc((size_t)NBUK * BCAP * 8);
  uint32_t* csr   = (uint32_t*)alloc((size_t)N_NODES * MAXDEG * 4);

  pack_cast<<<PACK_BLOCKS + CAST_BLOCKS, 256, 0, stream>>>(
      Wmsg, Wih, Whh, hv, W1p, W2p, we, hvh, bcur);
  bin_count<<<NBC, 256, 0, stream>>>(src, dst, he, bcur, barr);
  bin_place<<<NBUK, 256, 0, stream>>>(bcur, barr, csr, deg_i);

  float* outp = (float*)d_out;
  const int ugrid = (NTILES + 3) / 4;  // 782
  for (int t = 0; t < TROUNDS; ++t) {
    gather_h<<<(N_NODES + 3) / 4, 256, 0, stream>>>(hvh, deg_i, csr, S_h, hsum, deg_f, N_NODES);
    u1_kernel<<<ugrid, 256, 0, stream>>>(
        hvh, S_h, deg_f, hsum, W1p + (size_t)t * W1PT,
        we + (size_t)t * 256, bmsg + (size_t)t * 256, a_buf);
    u2_kernel<<<ugrid, 256, 0, stream>>>(
        a_buf, hvh, W2p + (size_t)t * W2PT,
        bih + (size_t)t * 384, bhh + (size_t)t * 384,
        (t == TROUNDS - 1) ? outp : (float*)nullptr,
        (t < TROUNDS - 1) ? hvh : (_Float16*)nullptr);
  }
  (void)in_sizes; (void)n_in; (void)out_size; (void)ws_size;
}